// Round 13
// baseline (1733.565 us; speedup 1.0000x reference)
//
#include <hip/hip_runtime.h>
#include <hip/hip_cooperative_groups.h>
#include <hip/hip_bf16.h>
#include <math.h>

namespace cg = cooperative_groups;
typedef __hip_bfloat16 bf16;

#define LN_EPS 1e-5f

__device__ __forceinline__ float b2f(bf16 x){ return __bfloat162float(x); }
__device__ __forceinline__ float sanit(float s){ return fminf(fmaxf(s, -80.f), 80.f); }

__device__ __forceinline__ void stc(float* p, float v){ *p = v; }
__device__ __forceinline__ void stc(bf16* p, float v){ *p = __float2bfloat16(v); }

__device__ __forceinline__ short f2s(float f){
    union { __hip_bfloat16 h; short s; } u; u.h = __float2bfloat16(f); return u.s;
}
__device__ __forceinline__ float s2f(short s){
    union { short s; __hip_bfloat16 h; } u; u.s = s; return b2f(u.h);
}

using short8  = __attribute__((ext_vector_type(8))) short;
using floatx4 = __attribute__((ext_vector_type(4))) float;

__device__ __forceinline__ short8 load8(const float* p){
    float4 a1 = *(const float4*)p; float4 a2 = *(const float4*)(p+4);
    return (short8){ f2s(a1.x),f2s(a1.y),f2s(a1.z),f2s(a1.w),
                     f2s(a2.x),f2s(a2.y),f2s(a2.z),f2s(a2.w) };
}
__device__ __forceinline__ short8 load8(const bf16* p){ return *(const short8*)p; }

// ------- fused setup: blocks [0,12544) ln_cast | [12544,19456) weight cvt |
//         [19456,21760) seed transpose ------------------------------------
__global__ void setup_fused(const float* __restrict__ x, const float* __restrict__ g,
                            const float* __restrict__ bb, bf16* __restrict__ xln,
                            bf16* __restrict__ xh, float* __restrict__ tmpz,
                            const float* __restrict__ wq, const float* __restrict__ wk,
                            const float* __restrict__ wv, const float* __restrict__ m1,
                            const float* __restrict__ m2, const float* __restrict__ qkv,
                            const float* __restrict__ proj, const float* __restrict__ bm1,
                            const float* __restrict__ bm2, bf16* __restrict__ wdst,
                            const float* __restrict__ sw, bf16* __restrict__ swt)
{
    int blk = blockIdx.x; int tid = threadIdx.x;
    if (blk < 12544){
        int token = blk; int d = tid;
        int w = d >> 6, lane = d & 63;
        __shared__ float part[8];
        float v = x[(size_t)token*256 + d];
        float s = v;
        #pragma unroll
        for (int off=32; off>0; off>>=1) s += __shfl_down(s, off);
        if (lane==0) part[w] = s;
        __syncthreads();
        float mean = (part[0]+part[1]+part[2]+part[3]) * (1.f/256.f);
        float dev = v - mean;
        float q = dev*dev;
        __syncthreads();
        #pragma unroll
        for (int off=32; off>0; off>>=1) q += __shfl_down(q, off);
        if (lane==0) part[w+4] = q;
        __syncthreads();
        float var = (part[4]+part[5]+part[6]+part[7]) * (1.f/256.f);
        float r = dev*rsqrtf(var+LN_EPS)*g[d] + bb[d];
        size_t o = (size_t)token*256+d;
        xln[o] = __float2bfloat16(r);
        xh[o]  = __float2bfloat16(v);
        if (token < 3136) tmpz[(size_t)token*256 + d] = 0.f;
    } else if (blk < 19456){
        int i = (blk-12544)*256 + tid;
        const float* src; int off;
        if      (i <   65536){ src=wq;   off=i; }
        else if (i <  131072){ src=wk;   off=i-65536; }
        else if (i <  196608){ src=wv;   off=i-131072; }
        else if (i <  327680){ src=m1;   off=i-196608; }
        else if (i <  458752){ src=m2;   off=i-327680; }
        else if (i <  851968){ src=qkv;  off=i-458752; }
        else if (i <  983040){ src=proj; off=i-851968; }
        else if (i < 1376256){ src=bm1;  off=i-983040; }
        else                 { src=bm2;  off=i-1376256; }
        wdst[i] = __float2bfloat16(src[off]);
    } else {
        int idx = (blk-19456)*256 + tid;   // 256*2304
        int o = idx/2304; int rem = idx - o*2304; int pos = rem>>8; int ci = rem&255;
        swt[idx] = __float2bfloat16(sw[(size_t)o*2304 + ci*9 + pos]);
    }
}

// ---------------- LayerNorm over D=256 (transformer tail) -----------------
template<typename TO>
__global__ void ln256_kernel(const float* __restrict__ in, const float* __restrict__ g,
                             const float* __restrict__ bb, TO* __restrict__ out, int addTo)
{
    int token = blockIdx.x; int d = threadIdx.x;
    int w = d >> 6, lane = d & 63;
    __shared__ float part[8];
    float v = in[(size_t)token*256 + d];
    float s = v;
    #pragma unroll
    for (int off=32; off>0; off>>=1) s += __shfl_down(s, off);
    if (lane==0) part[w] = s;
    __syncthreads();
    float mean = (part[0]+part[1]+part[2]+part[3]) * (1.f/256.f);
    float dev = v - mean;
    float q = dev*dev;
    __syncthreads();
    #pragma unroll
    for (int off=32; off>0; off>>=1) q += __shfl_down(q, off);
    if (lane==0) part[w+4] = q;
    __syncthreads();
    float var = (part[4]+part[5]+part[6]+part[7]) * (1.f/256.f);
    float r = dev*rsqrtf(var+LN_EPS)*g[d] + bb[d];
    size_t o = (size_t)token*256+d;
    if (addTo) out[o] += r; else stc(&out[o], r);
}

// ---------------- MFMA GEMM, ping-pong LDS (transformer tail) -------------
template<typename TA, typename TC>
__global__ __launch_bounds__(128) void gemm_mfma(const TA* __restrict__ A,
                       const bf16* __restrict__ W,
                       const float* __restrict__ bias, const float* __restrict__ resid,
                       TC* __restrict__ C, int M, int N, int K, int do_gelu)
{
    __shared__ __align__(16) short As[2][32*40];
    __shared__ __align__(16) short Ws[2][64*40];
    int t = threadIdx.x;
    int n0 = blockIdx.x*64, m0 = blockIdx.y*32;
    int lane = t & 63, w = t >> 6;
    int quad = lane >> 4, mrow = lane & 15;
    floatx4 acc[4] = {{0,0,0,0},{0,0,0,0},{0,0,0,0},{0,0,0,0}};
    int r  = t >> 2;
    int kq = (t & 3) * 8;
    const TA*   Arow  = A + (size_t)(m0 + r)*K + kq;
    const bf16* Wrow0 = W + (size_t)(n0 + r)*K + kq;
    const bf16* Wrow1 = W + (size_t)(n0 + r + 32)*K + kq;

    short8 av  = load8(Arow);
    short8 wv0 = load8(Wrow0);
    short8 wv1 = load8(Wrow1);
    *(short8*)&As[0][r*40 + kq] = av;
    *(short8*)&Ws[0][r*40 + kq] = wv0;
    *(short8*)&Ws[0][(r+32)*40 + kq] = wv1;
    __syncthreads();

    int nb = K >> 5;
    int cur = 0;
    for (int i = 0; i < nb; i++){
        if (i+1 < nb){
            int k0 = (i+1) << 5;
            av  = load8(Arow + k0);
            wv0 = load8(Wrow0 + k0);
            wv1 = load8(Wrow1 + k0);
        }
        short8 af = *(short8*)&As[cur][(w*16 + mrow)*40 + quad*8];
        #pragma unroll
        for (int nt=0; nt<4; nt++){
            short8 bfv = *(short8*)&Ws[cur][(nt*16 + mrow)*40 + quad*8];
            acc[nt] = __builtin_amdgcn_mfma_f32_16x16x32_bf16(af, bfv, acc[nt], 0, 0, 0);
        }
        if (i+1 < nb){
            int nxt = cur ^ 1;
            *(short8*)&As[nxt][r*40 + kq] = av;
            *(short8*)&Ws[nxt][r*40 + kq] = wv0;
            *(short8*)&Ws[nxt][(r+32)*40 + kq] = wv1;
            __syncthreads();
            cur = nxt;
        }
    }
    #pragma unroll
    for (int nt=0; nt<4; nt++){
        int col = n0 + nt*16 + mrow;
        float bv = bias ? bias[col] : 0.f;
        #pragma unroll
        for (int rr=0; rr<4; rr++){
            int row = m0 + w*16 + quad*4 + rr;
            float v = acc[nt][rr] + bv;
            if (do_gelu) v = 0.5f*v*(1.0f+erff(v*0.70710678118654752f));
            size_t o = (size_t)row*N + col;
            if (resid) v += resid[o];
            stc(&C[o], v);
        }
    }
}

// ------- merged K/V projection + seed conv, one dispatch ------------------
__global__ __launch_bounds__(128) void kv_conv(const bf16* __restrict__ xln,
                       const bf16* __restrict__ xh, const bf16* __restrict__ wk,
                       const bf16* __restrict__ wv, bf16* __restrict__ kp,
                       bf16* __restrict__ vp, const bf16* __restrict__ wt,
                       float* __restrict__ Cconv)
{
    __shared__ __align__(16) short As[2][32*40];
    __shared__ __align__(16) short Ws[2][64*40];
    int t = threadIdx.x;
    int lane = t & 63, w = t >> 6;
    int quad = lane >> 4, mrow = lane & 15;
    int r  = t >> 2;
    int kq = (t & 3) * 8;
    floatx4 acc[4] = {{0,0,0,0},{0,0,0,0},{0,0,0,0},{0,0,0,0}};
    int z = blockIdx.z;
    int n0 = blockIdx.x*64;

    if (z < 2){
        const int N = 256, K = 256;
        int m0 = blockIdx.y*32;
        const bf16* A = z ? xh : xln;
        const bf16* W = z ? wv : wk;
        bf16*       C = z ? vp : kp;
        const bf16* Arow  = A + (size_t)(m0 + r)*K + kq;
        const bf16* Wrow0 = W + (size_t)(n0 + r)*K + kq;
        const bf16* Wrow1 = W + (size_t)(n0 + r + 32)*K + kq;
        short8 av  = load8(Arow);
        short8 wv0 = load8(Wrow0);
        short8 wv1 = load8(Wrow1);
        *(short8*)&As[0][r*40 + kq] = av;
        *(short8*)&Ws[0][r*40 + kq] = wv0;
        *(short8*)&Ws[0][(r+32)*40 + kq] = wv1;
        __syncthreads();
        const int nb = K >> 5;
        int cur = 0;
        for (int i = 0; i < nb; i++){
            if (i+1 < nb){
                int k0 = (i+1) << 5;
                av  = load8(Arow + k0);
                wv0 = load8(Wrow0 + k0);
                wv1 = load8(Wrow1 + k0);
            }
            short8 af = *(short8*)&As[cur][(w*16 + mrow)*40 + quad*8];
            #pragma unroll
            for (int nt=0; nt<4; nt++){
                short8 bfv = *(short8*)&Ws[cur][(nt*16 + mrow)*40 + quad*8];
                acc[nt] = __builtin_amdgcn_mfma_f32_16x16x32_bf16(af, bfv, acc[nt], 0, 0, 0);
            }
            if (i+1 < nb){
                int nxt = cur ^ 1;
                *(short8*)&As[nxt][r*40 + kq] = av;
                *(short8*)&Ws[nxt][r*40 + kq] = wv0;
                *(short8*)&Ws[nxt][(r+32)*40 + kq] = wv1;
                __syncthreads();
                cur = nxt;
            }
        }
        #pragma unroll
        for (int nt=0; nt<4; nt++){
            int col = n0 + nt*16 + mrow;
            #pragma unroll
            for (int rr=0; rr<4; rr++){
                int row = m0 + w*16 + quad*4 + rr;
                C[(size_t)row*N + col] = __float2bfloat16(acc[nt][rr]);
            }
        }
    } else {
        int yy = blockIdx.y;
        if (yy >= 294) return;
        const int K = 2304, N = 256, KC = 768;
        int zc = yy / 98;
        int m0 = (yy - zc*98)*32;
        int m = m0 + r;
        int wo = m%28, ho = (m/28)%28, b = m/784;
        const bf16* Wrow0 = wt + (size_t)(n0 + r)*K + zc*KC + kq;
        const bf16* Wrow1 = wt + (size_t)(n0 + r + 32)*K + zc*KC + kq;
        int kh = zc;
        int ih = 2*ho + kh - 1;
        bool rowok = (ih>=0 && ih<56);
        auto loadA = [&](int k0)->short8{
            int kk = k0 + kq;
            int pos3 = kk >> 8;
            int ci = kk & 255;
            int iw = 2*wo + pos3 - 1;
            short8 a = {0,0,0,0,0,0,0,0};
            if (rowok && iw>=0 && iw<56)
                a = load8(xh + (((size_t)b*56 + ih)*56 + iw)*256 + ci);
            return a;
        };
        short8 av  = loadA(0);
        short8 wv0 = load8(Wrow0);
        short8 wv1 = load8(Wrow1);
        *(short8*)&As[0][r*40 + kq] = av;
        *(short8*)&Ws[0][r*40 + kq] = wv0;
        *(short8*)&Ws[0][(r+32)*40 + kq] = wv1;
        __syncthreads();
        const int nb = KC >> 5;
        int cur = 0;
        for (int i = 0; i < nb; i++){
            if (i+1 < nb){
                int k0 = (i+1) << 5;
                av  = loadA(k0);
                wv0 = load8(Wrow0 + k0);
                wv1 = load8(Wrow1 + k0);
            }
            short8 af = *(short8*)&As[cur][(w*16 + mrow)*40 + quad*8];
            #pragma unroll
            for (int nt=0; nt<4; nt++){
                short8 bfv = *(short8*)&Ws[cur][(nt*16 + mrow)*40 + quad*8];
                acc[nt] = __builtin_amdgcn_mfma_f32_16x16x32_bf16(af, bfv, acc[nt], 0, 0, 0);
            }
            if (i+1 < nb){
                int nxt = cur ^ 1;
                *(short8*)&As[nxt][r*40 + kq] = av;
                *(short8*)&Ws[nxt][r*40 + kq] = wv0;
                *(short8*)&Ws[nxt][(r+32)*40 + kq] = wv1;
                __syncthreads();
                cur = nxt;
            }
        }
        #pragma unroll
        for (int nt=0; nt<4; nt++){
            int col = n0 + nt*16 + mrow;
            #pragma unroll
            for (int rr=0; rr<4; rr++){
                int row = m0 + w*16 + quad*4 + rr;
                atomicAdd(&Cconv[(size_t)row*N + col], acc[nt][rr]);
            }
        }
    }
}

// ==================== persistent cooperative iteration kernel =============
struct MegaP {
    const bf16 *kproj, *vproj, *w_q, *w_m1, *w_m2;
    bf16 *tmph, *qbufh, *bigh, *xouth;
    float *tmp, *xout, *attng, *col;
    const float *lnog, *lnob, *blk1g, *blk1b, *b_m1, *b_m2, *rpb, *g_tau;
};

// GEMM stage: 64x64 tile, 4 waves, ping-pong LDS; grid-stride over tiles.
__device__ void gemm_stage(const bf16* A, const bf16* W, const float* bias,
                           bf16* Cb, float* Cf, int M, int N, int K, int do_gelu,
                           char* smem)
{
    short* As = (short*)smem;       // 2 x 2560 shorts
    short* Ws = As + 5120;          // 2 x 2560 shorts
    int t = threadIdx.x;
    int lane = t & 63, w = t >> 6;
    int quad = lane >> 4, mrow = lane & 15;
    int r = t >> 2, kq = (t & 3)*8;
    int ntN = N >> 6;
    int ntot = (M >> 6) * ntN;
    for (int tile = blockIdx.x; tile < ntot; tile += gridDim.x){
        int m0 = (tile / ntN) << 6, n0 = (tile % ntN) << 6;
        floatx4 acc[4] = {{0,0,0,0},{0,0,0,0},{0,0,0,0},{0,0,0,0}};
        const bf16* Arow = A + (size_t)(m0 + r)*K + kq;
        const bf16* Wrow = W + (size_t)(n0 + r)*K + kq;
        short8 av = load8(Arow);
        short8 wv = load8(Wrow);
        __syncthreads();            // LDS reuse guard (prev tile / prev stage)
        *(short8*)&As[r*40 + kq] = av;
        *(short8*)&Ws[r*40 + kq] = wv;
        __syncthreads();
        int nb = K >> 5, cur = 0;
        for (int i = 0; i < nb; i++){
            if (i+1 < nb){
                int k0 = (i+1) << 5;
                av = load8(Arow + k0);
                wv = load8(Wrow + k0);
            }
            short8 af = *(short8*)&As[cur*2560 + (w*16+mrow)*40 + quad*8];
            #pragma unroll
            for (int nt=0; nt<4; nt++){
                short8 bfv = *(short8*)&Ws[cur*2560 + (nt*16+mrow)*40 + quad*8];
                acc[nt] = __builtin_amdgcn_mfma_f32_16x16x32_bf16(af, bfv, acc[nt], 0,0,0);
            }
            if (i+1 < nb){
                int nxt = cur ^ 1;
                *(short8*)&As[nxt*2560 + r*40 + kq] = av;
                *(short8*)&Ws[nxt*2560 + r*40 + kq] = wv;
                __syncthreads();
                cur = nxt;
            }
        }
        #pragma unroll
        for (int nt=0; nt<4; nt++){
            int col = n0 + nt*16 + mrow;
            float bv = bias ? bias[col] : 0.f;
            #pragma unroll
            for (int rr=0; rr<4; rr++){
                int row = m0 + w*16 + quad*4 + rr;
                float v = acc[nt][rr] + bv;
                if (do_gelu) v = 0.5f*v*(1.0f+erff(v*0.70710678118654752f));
                size_t o = (size_t)row*N + col;
                if (Cf) Cf[o] = v; else Cb[o] = __float2bfloat16(v);
            }
        }
    }
}

__device__ void lnaddln_stage(const float* in, const float* resid, const float* g1,
                              const float* b1, const float* g2, const float* b2,
                              float* xout, bf16* tmph, float* colz, char* smem)
{
    float* part = (float*)smem;
    int d = threadIdx.x;
    int w = d >> 6, lane = d & 63;
    for (int token = blockIdx.x; token < 3136; token += gridDim.x){
        __syncthreads();
        size_t o = (size_t)token*256 + d;
        if (d == 0) colz[token] = 0.f;
        float v = in[o];
        float s = v;
        #pragma unroll
        for (int off=32; off>0; off>>=1) s += __shfl_down(s, off);
        if (lane==0) part[w] = s;
        __syncthreads();
        float mean = (part[0]+part[1]+part[2]+part[3]) * (1.f/256.f);
        float dev = v - mean;
        float q = dev*dev;
        __syncthreads();
        #pragma unroll
        for (int off=32; off>0; off>>=1) q += __shfl_down(q, off);
        if (lane==0) part[w+4] = q;
        __syncthreads();
        float var = (part[4]+part[5]+part[6]+part[7]) * (1.f/256.f);
        float r = dev*rsqrtf(var+LN_EPS)*g1[d] + b1[d];
        float sx = (resid ? resid[o] : 0.f) + r;
        xout[o] = sx;
        __syncthreads();
        float s2 = sx;
        #pragma unroll
        for (int off=32; off>0; off>>=1) s2 += __shfl_down(s2, off);
        if (lane==0) part[w] = s2;
        __syncthreads();
        float mean2 = (part[0]+part[1]+part[2]+part[3]) * (1.f/256.f);
        float dev2 = sx - mean2;
        float q2 = dev2*dev2;
        __syncthreads();
        #pragma unroll
        for (int off=32; off>0; off>>=1) q2 += __shfl_down(q2, off);
        if (lane==0) part[w+4] = q2;
        __syncthreads();
        float var2 = (part[4]+part[5]+part[6]+part[7]) * (1.f/256.f);
        tmph[o] = __float2bfloat16(dev2*rsqrtf(var2+LN_EPS)*g2[d] + b2[d]);
    }
}

__device__ void grpattn_stage(const bf16* kproj, const bf16* qbuf, const float* rpb,
                              const float* g_tau, float* attn, float* col, char* smem)
{
    short* Ks = (short*)smem;            // 7168 shorts
    short* Qs = Ks + 7168;               // 21504 shorts
    float* sc = (float*)(smem + 57344);  // 252 floats
    float* pr = sc + 252;                // 252 floats
    int tid = threadIdx.x;
    for (int blk = blockIdx.x; blk < 448; blk += gridDim.x){
        __syncthreads();
        int i = blk % 28; int bn = blk / 28; int n = bn & 3; int b = bn >> 2;
        int sh = n>>1, sw = n&1;
        int i0 = min(max(i-1,0),25);
        for (int u = tid; u < 28*32; u += 256){
            int j = u >> 5, c = u & 31;
            *(short8*)&Ks[j*256 + c*8] =
                *(const short8*)(kproj + ((size_t)b*3136 + (2*i+sh)*56 + (2*j+sw))*256 + c*8);
        }
        for (int u = tid; u < 3*28*32; u += 256){
            int rr = u / (28*32); int rem = u - rr*(28*32);
            int j = rem >> 5, c = rem & 31;
            *(short8*)&Qs[(rr*28 + j)*256 + c*8] =
                *(const short8*)(qbuf + ((size_t)b*784 + (i0+rr)*28 + j)*256 + c*8);
        }
        __syncthreads();
        float scale = expf(g_tau[0]);
        if (tid < 252){
            int pix = tid / 9, l = tid - (tid/9)*9;
            int j0 = min(max(pix-1,0),25);
            int qr = l/3, qj = j0 + (l - qr*3);
            const short* kp = &Ks[pix*256];
            const short* qp = &Qs[(qr*28 + qj)*256];
            float p = 0.f;
            for (int c = 0; c < 32; c++){
                short8 k8 = *(const short8*)(kp + c*8);
                short8 q8 = *(const short8*)(qp + c*8);
                #pragma unroll
                for (int d=0; d<8; d++) p += s2f(k8[d])*s2f(q8[d]);
            }
            sc[pix*9 + l] = sanit((p + rpb[n*9+l])*scale);
        }
        __syncthreads();
        if (tid < 28){
            float m = -1e30f;
            for (int l=0;l<9;l++) m = fmaxf(m, sc[tid*9+l]);
            float sum=0.f; float e[9];
            for (int l=0;l<9;l++){ e[l]=expf(sc[tid*9+l]-m); sum+=e[l]; }
            float inv = 1.f/fmaxf(sum,1e-30f);
            for (int l=0;l<9;l++) pr[tid*9+l] = e[l]*inv + 1e-6f;
        }
        __syncthreads();
        if (tid < 252){
            int pix = tid/9, l = tid - (tid/9)*9;
            float a = pr[pix*9+l];
            int idx = (b*4+n)*784 + i*28 + pix;
            attn[(size_t)idx*9 + l] = a;
            int j0 = min(max(pix-1,0),25);
            int qi = i0 + l/3, qj = j0 + l%3;
            atomicAdd(&col[b*784 + qi*28 + qj], a);
        }
    }
}

__device__ void grpav_stage(const float* attn, const float* col, const bf16* vproj,
                            float* xout, bf16* xouth)
{
    int d = threadIdx.x;
    for (int idx = blockIdx.x; idx < 3136; idx += gridDim.x){
        int j = idx%28; int i = (idx/28)%28; int b = idx/784;
        int i0 = min(max(i-1,0),25), j0 = min(max(j-1,0),25);
        float acc = 0.f;
        for (int n=0; n<4; n++){
            int sh = n>>1, sw = n&1;
            const float* ap = attn + ((size_t)(b*4+n)*784 + i*28+j)*9;
            for (int l=0; l<9; l++){
                int qi = i0 + l/3, qj = j0 + l%3;
                float dv = col[b*784 + qi*28+qj] + 1e-8f;
                acc += (ap[l]/dv) * b2f(vproj[((size_t)b*3136 + (2*qi+sh)*56 + (2*qj+sw))*256 + d]);
            }
        }
        size_t o = (size_t)idx*256 + d;
        float nv = xout[o] + acc;
        xout[o] = nv;
        xouth[o] = __float2bfloat16(nv);
    }
}

__global__ __launch_bounds__(256, 2) void mega_iter(MegaP p)
{
    cg::grid_group grid = cg::this_grid();
    __shared__ __align__(16) char smem[59392];
    // stage 0: xout = LN_out(seed); tmph = LN_out(xout); col = 0
    lnaddln_stage(p.tmp, nullptr, p.lnog, p.lnob, p.lnog, p.lnob, p.xout, p.tmph, p.col, smem);
    grid.sync();
    for (int it = 0; it < 3; it++){
        gemm_stage(p.tmph, p.w_q, nullptr, p.qbufh, nullptr, 3136, 256, 256, 0, smem);
        grid.sync();
        grpattn_stage(p.kproj, p.qbufh, p.rpb, p.g_tau, p.attng, p.col, smem);
        grid.sync();
        grpav_stage(p.attng, p.col, p.vproj, p.xout, p.xouth);
        grid.sync();
        gemm_stage(p.xouth, p.w_m1, p.b_m1, p.bigh, nullptr, 3136, 512, 256, 1, smem);
        grid.sync();
        gemm_stage(p.bigh, p.w_m2, p.b_m2, nullptr, p.tmp, 3136, 256, 512, 0, smem);
        grid.sync();
        const float* g2 = (it < 2) ? p.lnog : p.blk1g;
        const float* b2 = (it < 2) ? p.lnob : p.blk1b;
        lnaddln_stage(p.tmp, p.xout, p.lnog, p.lnob, g2, b2, p.xout, p.tmph, p.col, smem);
        grid.sync();
    }
}

// ------- Block attention (KB=7), row-tiled, RoPE fused in staging ---------
__global__ __launch_bounds__(256) void blk_attn_row(const bf16* __restrict__ qkv,
                                                    bf16* __restrict__ obuf)
{
    int blk = blockIdx.x;             // (b*28 + i)*8 + h
    int h = blk & 7; int rest = blk >> 3;
    int i = rest % 28; int b = rest / 28;
    int tid = threadIdx.x;
    int i0 = min(max(i-3,0),21);

    __shared__ float Ks[7*28*32];
    __shared__ float Vs[7*28*32];
    __shared__ float Qs[28*32];
    __shared__ float Ps[28*52];

    const float LOG1E4_16 = 0.5756462732485115f;   // ln(10000)/16

    for (int idx = tid; idx < 196*4; idx += 256){
        int pos = idx >> 2, u8 = idx & 3;
        int ki = i0 + pos/28, kj = pos - (pos/28)*28;
        int ttok = ki*28 + kj;
        const bf16* base = qkv + ((size_t)(b*784 + ttok))*768 + h*32 + u8*8;
        short8 k8 = *(const short8*)(base + 256);
        short8 v8 = *(const short8*)(base + 512);
        float f[8];
        #pragma unroll
        for (int d=0; d<8; d++) f[d] = s2f(k8[d]);
        #pragma unroll
        for (int m2=0; m2<4; m2++){
            int u = u8*4 + m2;
            float ang = (float)ttok * expf(-(float)u * LOG1E4_16);
            float c = cosf(ang), s = sinf(ang);
            float x0 = f[2*m2], x1 = f[2*m2+1];
            f[2*m2]   = x0*c - x1*s;
            f[2*m2+1] = x1*c + x0*s;
        }
        #pragma unroll
        for (int d=0; d<8; d++){
            Ks[pos*32 + u8*8 + d] = f[d];
            Vs[pos*32 + u8*8 + d] = s2f(v8[d]);
        }
    }
    for (int idx = tid; idx < 28*4; idx += 256){
        int tt = idx >> 2, u8 = idx & 3;
        int ttok = i*28 + tt;
        const bf16* base = qkv + ((size_t)(b*784 + ttok))*768 + h*32 + u8*8;
        short8 q8 = *(const short8*)base;
        float f[8];
        #pragma unroll
        for (int d=0; d<8; d++) f[d] = s2f(q8[d]);
        #pragma unroll
        for (int m2=0; m2<4; m2++){
            int u = u8*4 + m2;
            float ang = (float)ttok * expf(-(float)u * LOG1E4_16);
            float c = cosf(ang), s = sinf(ang);
            float x0 = f[2*m2], x1 = f[2*m2+1];
            f[2*m2]   = x0*c - x1*s;
            f[2*m2+1] = x1*c + x0*s;
        }
        #pragma unroll
        for (int d=0; d<8; d++) Qs[tt*32 + u8*8 + d] = f[d];
    }
    __syncthreads();

    int tt = tid >> 3, s = tid & 7;
    float sc[7];
    float mx = -1e30f;
    int j0 = min(max(tt-3,0),21);
    if (tt < 28){
        int c = 0;
        for (int l = s; l < 49; l += 8, c++){
            int ki = l/7, kj = j0 + l - (l/7)*7;
            const float4* kp = (const float4*)&Ks[(ki*28+kj)*32];
            const float4* qp = (const float4*)&Qs[tt*32];
            float p = 0.f;
            #pragma unroll
            for (int d=0; d<8; d++){
                float4 kv4 = kp[d], qv4 = qp[d];
                p += qv4.x*kv4.x + qv4.y*kv4.y + qv4.z*kv4.z + qv4.w*kv4.w;
            }
            sc[c] = sanit(p * 0.17677669529663687f);
            mx = fmaxf(mx, sc[c]);
        }
    }
    #pragma unroll
    for (int off=1; off<8; off<<=1) mx = fmaxf(mx, __shfl_xor(mx, off, 8));
    float sm = 0.f;
    if (tt < 28){
        int c = 0;
        for (int l = s; l < 49; l += 8, c++){ sc[c] = expf(sc[c]-mx); sm += sc[c]; }
    }
    #pragma unroll
    for (int off=1; off<8; off<<=1) sm += __shfl_xor(sm, off, 8);
    if (tt < 28){
        float inv = 1.f/fmaxf(sm, 1e-30f);
        int c = 0;
        for (int l = s; l < 49; l += 8, c++) Ps[tt*52 + l] = sc[c]*inv;
    }
    __syncthreads();

    for (int o = tid; o < 28*32; o += 256){
        int t2 = o >> 5, d = o & 31;
        int jj0 = min(max(t2-3,0),21);
        float acc = 0.f;
        #pragma unroll 7
        for (int l=0; l<49; l++){
            int ki = l/7, kj = jj0 + l - (l/7)*7;
            acc += Ps[t2*52 + l] * Vs[(ki*28+kj)*32 + d];
        }
        obuf[((size_t)(b*784 + i*28 + t2))*256 + h*32 + d] = __float2bfloat16(acc);
    }
}

// ==========================================================================
extern "C" void kernel_launch(void* const* d_in, const int* in_sizes, int n_in,
                              void* d_out, int out_size, void* d_ws, size_t ws_size,
                              hipStream_t stream) {
    const float* x         = (const float*)d_in[0];
    const float* g_seed_w  = (const float*)d_in[1];
    const float* g_q_w     = (const float*)d_in[2];
    const float* g_k_w     = (const float*)d_in[3];
    const float* g_v_w     = (const float*)d_in[4];
    const float* g_mlp_w1  = (const float*)d_in[5];
    const float* g_mlp_b1  = (const float*)d_in[6];
    const float* g_mlp_w2  = (const float*)d_in[7];
    const float* g_mlp_b2  = (const float*)d_in[8];
    const float* g_ln_in_g = (const float*)d_in[9];
    const float* g_ln_in_b = (const float*)d_in[10];
    const float* g_ln_out_g= (const float*)d_in[11];
    const float* g_ln_out_b= (const float*)d_in[12];
    const float* g_tau     = (const float*)d_in[13];
    const float* g_rpb     = (const float*)d_in[14];
    const float* blk_ln1_g = (const float*)d_in[15];
    const float* blk_ln1_b = (const float*)d_in[16];
    const float* blk_qkv_w = (const float*)d_in[17];
    const float* blk_proj_w= (const float*)d_in[18];
    const float* blk_proj_b= (const float*)d_in[19];
    const float* blk_ln2_g = (const float*)d_in[20];
    const float* blk_ln2_b = (const float*)d_in[21];
    const float* blk_mlp_w1= (const float*)d_in[22];
    const float* blk_mlp_b1= (const float*)d_in[23];
    const float* blk_mlp_w2= (const float*)d_in[24];
    const float* blk_mlp_b2= (const float*)d_in[25];

    // workspace layout — 11,732,288 floats = 46.9 MB (ws ≈ 268 MB)
    float* f      = (float*)d_ws;
    bf16*  wbuf   = (bf16*)d_ws;                 // 2359296 bf16 = 1179648 f
    bf16*  kproj  = (bf16*)(f + 1179648);        // 3211264 bf16
    bf16*  vproj  = (bf16*)(f + 2785280);        // 3211264 bf16
    float* xout   = f + 4390912;                 // 802816
    float* tmp    = f + 5193728;                 // 802816
    bf16*  tmph   = (bf16*)(f + 5996544);        // 802816 bf16
    bf16*  qbufh  = (bf16*)(f + 6397952);        // 802816 bf16
    bf16*  bigh   = (bf16*)(f + 6799360);        // 2408448 bf16
    float* attng  = f + 8003584;                 // 112896
    float* col    = f + 8116480;                 // 3136
    bf16*  xln    = (bf16*)(f + 8119616);        // 3211264 bf16
    bf16*  xh     = (bf16*)(f + 9725248);        // 3211264 bf16
    bf16*  xouth  = (bf16*)(f + 11330880);       // 802816 bf16

    bf16* w_q    = wbuf;
    bf16* w_k    = wbuf + 65536;
    bf16* w_v    = wbuf + 131072;
    bf16* w_m1   = wbuf + 196608;
    bf16* w_m2   = wbuf + 327680;
    bf16* w_qkv  = wbuf + 458752;   // 2 layers x 196608
    bf16* w_proj = wbuf + 851968;   // 2 x 65536
    bf16* w_bm1  = wbuf + 983040;   // 2 x 196608
    bf16* w_bm2  = wbuf + 1376256;  // 2 x 196608
    bf16* w_seed = wbuf + 1769472;  // 589824

    // ---- setup ----
    setup_fused<<<21760, 256, 0, stream>>>(x, g_ln_in_g, g_ln_in_b, xln, xh, tmp,
                                           g_q_w, g_k_w, g_v_w, g_mlp_w1, g_mlp_w2,
                                           blk_qkv_w, blk_proj_w, blk_mlp_w1, blk_mlp_w2,
                                           wbuf, g_seed_w, w_seed);
    kv_conv<<<dim3(4,392,3), 128, 0, stream>>>(xln, xh, w_k, w_v, kproj, vproj, w_seed, tmp);

    // ---- persistent cooperative kernel: seed LN + 3 group-attn iterations
    MegaP p;
    p.kproj = kproj; p.vproj = vproj; p.w_q = w_q; p.w_m1 = w_m1; p.w_m2 = w_m2;
    p.tmph = tmph; p.qbufh = qbufh; p.bigh = bigh; p.xouth = xouth;
    p.tmp = tmp; p.xout = xout; p.attng = attng; p.col = col;
    p.lnog = g_ln_out_g; p.lnob = g_ln_out_b; p.blk1g = blk_ln1_g; p.blk1b = blk_ln1_b;
    p.b_m1 = g_mlp_b1; p.b_m2 = g_mlp_b2; p.rpb = g_rpb; p.g_tau = g_tau;
    int bpc = 0;
    hipOccupancyMaxActiveBlocksPerMultiprocessor(&bpc, mega_iter, 256, 0);
    if (bpc < 1) bpc = 1;
    int grid = bpc * 256; if (grid > 512) grid = 512;
    void* args[] = { (void*)&p };
    hipLaunchCooperativeKernel((void*)mega_iter, dim3(grid), dim3(256), args, 0, stream);

    // ---- DEPTH transformer blocks (tmph holds LN1(xout) at loop entry) ----
    for (int l=0; l<2; l++){
        gemm_mfma<bf16,bf16><<<dim3(12,98), 128, 0, stream>>>(tmph, w_qkv + (size_t)l*196608, nullptr, nullptr, bigh, 3136,768,256, 0);
        blk_attn_row<<<896, 256, 0, stream>>>(bigh, qbufh);
        gemm_mfma<bf16,float><<<dim3(4,98), 128, 0, stream>>>(qbufh, w_proj + (size_t)l*65536, blk_proj_b + l*256, xout, xout, 3136,256,256, 0);
        ln256_kernel<bf16><<<3136, 256, 0, stream>>>(xout, blk_ln2_g + l*256, blk_ln2_b + l*256, tmph, 0);
        gemm_mfma<bf16,bf16><<<dim3(12,98), 128, 0, stream>>>(tmph, w_bm1 + (size_t)l*196608, blk_mlp_b1 + l*768, nullptr, bigh, 3136,768,256, 1);
        if (l==0){
            gemm_mfma<bf16,float><<<dim3(4,98), 128, 0, stream>>>(bigh, w_bm2, blk_mlp_b2, xout, xout, 3136,256,768, 0);
            ln256_kernel<bf16><<<3136, 256, 0, stream>>>(xout, blk_ln1_g + 256, blk_ln1_b + 256, tmph, 0);
        } else {
            gemm_mfma<bf16,float><<<dim3(4,98), 128, 0, stream>>>(bigh, w_bm2 + 196608, blk_mlp_b2 + 256, xout, (float*)d_out, 3136,256,768, 0);
        }
    }
}

// Round 14
// 500.511 us; speedup vs baseline: 3.4636x; 3.4636x over previous
//
#include <hip/hip_runtime.h>
#include <hip/hip_bf16.h>
#include <math.h>

typedef __hip_bfloat16 bf16;

#define LN_EPS 1e-5f

__device__ __forceinline__ float b2f(bf16 x){ return __bfloat162float(x); }
__device__ __forceinline__ float sanit(float s){ return fminf(fmaxf(s, -80.f), 80.f); }

__device__ __forceinline__ void stc(float* p, float v){ *p = v; }
__device__ __forceinline__ void stc(bf16* p, float v){ *p = __float2bfloat16(v); }

__device__ __forceinline__ short f2s(float f){
    union { __hip_bfloat16 h; short s; } u; u.h = __float2bfloat16(f); return u.s;
}
__device__ __forceinline__ float s2f(short s){
    union { short s; __hip_bfloat16 h; } u; u.s = s; return b2f(u.h);
}

using short8  = __attribute__((ext_vector_type(8))) short;
using floatx4 = __attribute__((ext_vector_type(4))) float;

__device__ __forceinline__ short8 load8(const float* p){
    float4 a1 = *(const float4*)p; float4 a2 = *(const float4*)(p+4);
    return (short8){ f2s(a1.x),f2s(a1.y),f2s(a1.z),f2s(a1.w),
                     f2s(a2.x),f2s(a2.y),f2s(a2.z),f2s(a2.w) };
}
__device__ __forceinline__ short8 load8(const bf16* p){ return *(const short8*)p; }

// ------- fused setup: blocks [0,12544) ln_cast | [12544,19456) weight cvt |
//         [19456,21760) seed transpose. Independent jobs overlap on CUs.
__global__ void setup_fused(const float* __restrict__ x, const float* __restrict__ g,
                            const float* __restrict__ bb, bf16* __restrict__ xln,
                            bf16* __restrict__ xh, float* __restrict__ tmpz,
                            const float* __restrict__ wq, const float* __restrict__ wk,
                            const float* __restrict__ wv, const float* __restrict__ m1,
                            const float* __restrict__ m2, const float* __restrict__ qkv,
                            const float* __restrict__ proj, const float* __restrict__ bm1,
                            const float* __restrict__ bm2, bf16* __restrict__ wdst,
                            const float* __restrict__ sw, bf16* __restrict__ swt)
{
    int blk = blockIdx.x; int tid = threadIdx.x;
    if (blk < 12544){
        int token = blk; int d = tid;
        int w = d >> 6, lane = d & 63;
        __shared__ float part[8];
        float v = x[(size_t)token*256 + d];
        float s = v;
        #pragma unroll
        for (int off=32; off>0; off>>=1) s += __shfl_down(s, off);
        if (lane==0) part[w] = s;
        __syncthreads();
        float mean = (part[0]+part[1]+part[2]+part[3]) * (1.f/256.f);
        float dev = v - mean;
        float q = dev*dev;
        __syncthreads();
        #pragma unroll
        for (int off=32; off>0; off>>=1) q += __shfl_down(q, off);
        if (lane==0) part[w+4] = q;
        __syncthreads();
        float var = (part[4]+part[5]+part[6]+part[7]) * (1.f/256.f);
        float r = dev*rsqrtf(var+LN_EPS)*g[d] + bb[d];
        size_t o = (size_t)token*256+d;
        xln[o] = __float2bfloat16(r);
        xh[o]  = __float2bfloat16(v);
        if (token < 3136) tmpz[(size_t)token*256 + d] = 0.f;
    } else if (blk < 19456){
        int i = (blk-12544)*256 + tid;
        const float* src; int off;
        if      (i <   65536){ src=wq;   off=i; }
        else if (i <  131072){ src=wk;   off=i-65536; }
        else if (i <  196608){ src=wv;   off=i-131072; }
        else if (i <  327680){ src=m1;   off=i-196608; }
        else if (i <  458752){ src=m2;   off=i-327680; }
        else if (i <  851968){ src=qkv;  off=i-458752; }
        else if (i <  983040){ src=proj; off=i-851968; }
        else if (i < 1376256){ src=bm1;  off=i-983040; }
        else                 { src=bm2;  off=i-1376256; }
        wdst[i] = __float2bfloat16(src[off]);
    } else {
        int idx = (blk-19456)*256 + tid;   // 256*2304
        int o = idx/2304; int rem = idx - o*2304; int pos = rem>>8; int ci = rem&255;
        swt[idx] = __float2bfloat16(sw[(size_t)o*2304 + ci*9 + pos]);
    }
}

// ------- fused: xout = (resid?) + LN1(in); tmph = bf16(LN2(xout)); col=0 --
__global__ void ln_add_ln(const float* __restrict__ in, const float* __restrict__ resid,
                          const float* __restrict__ g1, const float* __restrict__ b1,
                          const float* __restrict__ g2, const float* __restrict__ b2,
                          float* __restrict__ xout, bf16* __restrict__ tmph,
                          float* __restrict__ colz)
{
    int token = blockIdx.x; int d = threadIdx.x;
    int w = d >> 6, lane = d & 63;
    __shared__ float part[8];
    size_t o = (size_t)token*256 + d;
    if (d == 0) colz[token] = 0.f;
    float v = in[o];
    float s = v;
    #pragma unroll
    for (int off=32; off>0; off>>=1) s += __shfl_down(s, off);
    if (lane==0) part[w] = s;
    __syncthreads();
    float mean = (part[0]+part[1]+part[2]+part[3]) * (1.f/256.f);
    float dev = v - mean;
    float q = dev*dev;
    __syncthreads();
    #pragma unroll
    for (int off=32; off>0; off>>=1) q += __shfl_down(q, off);
    if (lane==0) part[w+4] = q;
    __syncthreads();
    float var = (part[4]+part[5]+part[6]+part[7]) * (1.f/256.f);
    float r = dev*rsqrtf(var+LN_EPS)*g1[d] + b1[d];
    float sx = (resid ? resid[o] : 0.f) + r;
    xout[o] = sx;
    __syncthreads();
    float s2 = sx;
    #pragma unroll
    for (int off=32; off>0; off>>=1) s2 += __shfl_down(s2, off);
    if (lane==0) part[w] = s2;
    __syncthreads();
    float mean2 = (part[0]+part[1]+part[2]+part[3]) * (1.f/256.f);
    float dev2 = sx - mean2;
    float q2 = dev2*dev2;
    __syncthreads();
    #pragma unroll
    for (int off=32; off>0; off>>=1) q2 += __shfl_down(q2, off);
    if (lane==0) part[w+4] = q2;
    __syncthreads();
    float var2 = (part[4]+part[5]+part[6]+part[7]) * (1.f/256.f);
    tmph[o] = __float2bfloat16(dev2*rsqrtf(var2+LN_EPS)*g2[d] + b2[d]);
}

// ---------------- LayerNorm over D=256: wave-shuffle reduction ------------
template<typename TO>
__global__ void ln256_kernel(const float* __restrict__ in, const float* __restrict__ g,
                             const float* __restrict__ bb, TO* __restrict__ out, int addTo)
{
    int token = blockIdx.x; int d = threadIdx.x;
    int w = d >> 6, lane = d & 63;
    __shared__ float part[8];
    float v = in[(size_t)token*256 + d];
    float s = v;
    #pragma unroll
    for (int off=32; off>0; off>>=1) s += __shfl_down(s, off);
    if (lane==0) part[w] = s;
    __syncthreads();
    float mean = (part[0]+part[1]+part[2]+part[3]) * (1.f/256.f);
    float dev = v - mean;
    float q = dev*dev;
    __syncthreads();
    #pragma unroll
    for (int off=32; off>0; off>>=1) q += __shfl_down(q, off);
    if (lane==0) part[w+4] = q;
    __syncthreads();
    float var = (part[4]+part[5]+part[6]+part[7]) * (1.f/256.f);
    float r = dev*rsqrtf(var+LN_EPS)*g[d] + bb[d];
    size_t o = (size_t)token*256+d;
    if (addTo) out[o] += r; else stc(&out[o], r);
}

// ---------------- MFMA GEMM, ping-pong double-buffered LDS ----------------
template<typename TA, typename TC>
__global__ __launch_bounds__(128) void gemm_mfma(const TA* __restrict__ A,
                       const bf16* __restrict__ W,
                       const float* __restrict__ bias, const float* __restrict__ resid,
                       TC* __restrict__ C, int M, int N, int K, int do_gelu)
{
    __shared__ __align__(16) short As[2][32*40];
    __shared__ __align__(16) short Ws[2][64*40];
    int t = threadIdx.x;
    int n0 = blockIdx.x*64, m0 = blockIdx.y*32;
    int lane = t & 63, w = t >> 6;
    int quad = lane >> 4, mrow = lane & 15;
    floatx4 acc[4] = {{0,0,0,0},{0,0,0,0},{0,0,0,0},{0,0,0,0}};
    int r  = t >> 2;
    int kq = (t & 3) * 8;
    const TA*   Arow  = A + (size_t)(m0 + r)*K + kq;
    const bf16* Wrow0 = W + (size_t)(n0 + r)*K + kq;
    const bf16* Wrow1 = W + (size_t)(n0 + r + 32)*K + kq;

    short8 av  = load8(Arow);
    short8 wv0 = load8(Wrow0);
    short8 wv1 = load8(Wrow1);
    *(short8*)&As[0][r*40 + kq] = av;
    *(short8*)&Ws[0][r*40 + kq] = wv0;
    *(short8*)&Ws[0][(r+32)*40 + kq] = wv1;
    __syncthreads();

    int nb = K >> 5;
    int cur = 0;
    for (int i = 0; i < nb; i++){
        if (i+1 < nb){
            int k0 = (i+1) << 5;
            av  = load8(Arow + k0);
            wv0 = load8(Wrow0 + k0);
            wv1 = load8(Wrow1 + k0);
        }
        short8 af = *(short8*)&As[cur][(w*16 + mrow)*40 + quad*8];
        #pragma unroll
        for (int nt=0; nt<4; nt++){
            short8 bfv = *(short8*)&Ws[cur][(nt*16 + mrow)*40 + quad*8];
            acc[nt] = __builtin_amdgcn_mfma_f32_16x16x32_bf16(af, bfv, acc[nt], 0, 0, 0);
        }
        if (i+1 < nb){
            int nxt = cur ^ 1;
            *(short8*)&As[nxt][r*40 + kq] = av;
            *(short8*)&Ws[nxt][r*40 + kq] = wv0;
            *(short8*)&Ws[nxt][(r+32)*40 + kq] = wv1;
            __syncthreads();
            cur = nxt;
        }
    }
    #pragma unroll
    for (int nt=0; nt<4; nt++){
        int col = n0 + nt*16 + mrow;
        float bv = bias ? bias[col] : 0.f;
        #pragma unroll
        for (int rr=0; rr<4; rr++){
            int row = m0 + w*16 + quad*4 + rr;
            float v = acc[nt][rr] + bv;
            if (do_gelu) v = 0.5f*v*(1.0f+erff(v*0.70710678118654752f));
            size_t o = (size_t)row*N + col;
            if (resid) v += resid[o];
            stc(&C[o], v);
        }
    }
}

// ------- merged K/V projection + seed conv, one dispatch ------------------
// z=0: kproj = xln@Wk^T   z=1: vproj = xh@Wv^T   (y in [0,392), M=12544)
// z=2: conv chunk = y/98, m0 = (y%98)*32 (y<294; atomicAdd into Cconv)
__global__ __launch_bounds__(128) void kv_conv(const bf16* __restrict__ xln,
                       const bf16* __restrict__ xh, const bf16* __restrict__ wk,
                       const bf16* __restrict__ wv, bf16* __restrict__ kp,
                       bf16* __restrict__ vp, const bf16* __restrict__ wt,
                       float* __restrict__ Cconv)
{
    __shared__ __align__(16) short As[2][32*40];
    __shared__ __align__(16) short Ws[2][64*40];
    int t = threadIdx.x;
    int lane = t & 63, w = t >> 6;
    int quad = lane >> 4, mrow = lane & 15;
    int r  = t >> 2;
    int kq = (t & 3) * 8;
    floatx4 acc[4] = {{0,0,0,0},{0,0,0,0},{0,0,0,0},{0,0,0,0}};
    int z = blockIdx.z;
    int n0 = blockIdx.x*64;

    if (z < 2){
        const int N = 256, K = 256;
        int m0 = blockIdx.y*32;
        const bf16* A = z ? xh : xln;
        const bf16* W = z ? wv : wk;
        bf16*       C = z ? vp : kp;
        const bf16* Arow  = A + (size_t)(m0 + r)*K + kq;
        const bf16* Wrow0 = W + (size_t)(n0 + r)*K + kq;
        const bf16* Wrow1 = W + (size_t)(n0 + r + 32)*K + kq;
        short8 av  = load8(Arow);
        short8 wv0 = load8(Wrow0);
        short8 wv1 = load8(Wrow1);
        *(short8*)&As[0][r*40 + kq] = av;
        *(short8*)&Ws[0][r*40 + kq] = wv0;
        *(short8*)&Ws[0][(r+32)*40 + kq] = wv1;
        __syncthreads();
        const int nb = K >> 5;
        int cur = 0;
        for (int i = 0; i < nb; i++){
            if (i+1 < nb){
                int k0 = (i+1) << 5;
                av  = load8(Arow + k0);
                wv0 = load8(Wrow0 + k0);
                wv1 = load8(Wrow1 + k0);
            }
            short8 af = *(short8*)&As[cur][(w*16 + mrow)*40 + quad*8];
            #pragma unroll
            for (int nt=0; nt<4; nt++){
                short8 bfv = *(short8*)&Ws[cur][(nt*16 + mrow)*40 + quad*8];
                acc[nt] = __builtin_amdgcn_mfma_f32_16x16x32_bf16(af, bfv, acc[nt], 0, 0, 0);
            }
            if (i+1 < nb){
                int nxt = cur ^ 1;
                *(short8*)&As[nxt][r*40 + kq] = av;
                *(short8*)&Ws[nxt][r*40 + kq] = wv0;
                *(short8*)&Ws[nxt][(r+32)*40 + kq] = wv1;
                __syncthreads();
                cur = nxt;
            }
        }
        #pragma unroll
        for (int nt=0; nt<4; nt++){
            int col = n0 + nt*16 + mrow;
            #pragma unroll
            for (int rr=0; rr<4; rr++){
                int row = m0 + w*16 + quad*4 + rr;
                C[(size_t)row*N + col] = __float2bfloat16(acc[nt][rr]);
            }
        }
    } else {
        int yy = blockIdx.y;
        if (yy >= 294) return;
        const int K = 2304, N = 256, KC = 768;
        int zc = yy / 98;
        int m0 = (yy - zc*98)*32;
        int m = m0 + r;
        int wo = m%28, ho = (m/28)%28, b = m/784;
        const bf16* Wrow0 = wt + (size_t)(n0 + r)*K + zc*KC + kq;
        const bf16* Wrow1 = wt + (size_t)(n0 + r + 32)*K + zc*KC + kq;
        int kh = zc;
        int ih = 2*ho + kh - 1;
        bool rowok = (ih>=0 && ih<56);
        auto loadA = [&](int k0)->short8{
            int kk = k0 + kq;
            int pos3 = kk >> 8;
            int ci = kk & 255;
            int iw = 2*wo + pos3 - 1;
            short8 a = {0,0,0,0,0,0,0,0};
            if (rowok && iw>=0 && iw<56)
                a = load8(xh + (((size_t)b*56 + ih)*56 + iw)*256 + ci);
            return a;
        };
        short8 av  = loadA(0);
        short8 wv0 = load8(Wrow0);
        short8 wv1 = load8(Wrow1);
        *(short8*)&As[0][r*40 + kq] = av;
        *(short8*)&Ws[0][r*40 + kq] = wv0;
        *(short8*)&Ws[0][(r+32)*40 + kq] = wv1;
        __syncthreads();
        const int nb = KC >> 5;
        int cur = 0;
        for (int i = 0; i < nb; i++){
            if (i+1 < nb){
                int k0 = (i+1) << 5;
                av  = loadA(k0);
                wv0 = load8(Wrow0 + k0);
                wv1 = load8(Wrow1 + k0);
            }
            short8 af = *(short8*)&As[cur][(w*16 + mrow)*40 + quad*8];
            #pragma unroll
            for (int nt=0; nt<4; nt++){
                short8 bfv = *(short8*)&Ws[cur][(nt*16 + mrow)*40 + quad*8];
                acc[nt] = __builtin_amdgcn_mfma_f32_16x16x32_bf16(af, bfv, acc[nt], 0, 0, 0);
            }
            if (i+1 < nb){
                int nxt = cur ^ 1;
                *(short8*)&As[nxt][r*40 + kq] = av;
                *(short8*)&Ws[nxt][r*40 + kq] = wv0;
                *(short8*)&Ws[nxt][(r+32)*40 + kq] = wv1;
                __syncthreads();
                cur = nxt;
            }
        }
        #pragma unroll
        for (int nt=0; nt<4; nt++){
            int col = n0 + nt*16 + mrow;
            #pragma unroll
            for (int rr=0; rr<4; rr++){
                int row = m0 + w*16 + quad*4 + rr;
                atomicAdd(&Cconv[(size_t)row*N + col], acc[nt][rr]);
            }
        }
    }
}

// -------- Group attention, row-tiled: one block per (b,n,i) ---------------
__global__ __launch_bounds__(256) void grp_attn_row(const bf16* __restrict__ kproj,
                                const bf16* __restrict__ qbuf,
                                const float* __restrict__ rpb, const float* __restrict__ g_tau,
                                float* __restrict__ attn, float* __restrict__ col)
{
    int blk = blockIdx.x;           // (b*4+n)*28 + i
    int i = blk % 28; int bn = blk / 28; int n = bn & 3; int b = bn >> 2;
    int tid = threadIdx.x;
    int sh = n>>1, sw = n&1;
    int i0 = min(max(i-1,0),25);
    __shared__ short Ks[28*256];
    __shared__ short Qs[3*28*256];
    __shared__ float sc[28*9];
    __shared__ float pr[28*9];

    for (int u = tid; u < 28*32; u += 256){
        int j = u >> 5, c = u & 31;
        *(short8*)&Ks[j*256 + c*8] =
            *(const short8*)(kproj + ((size_t)b*3136 + (2*i+sh)*56 + (2*j+sw))*256 + c*8);
    }
    for (int u = tid; u < 3*28*32; u += 256){
        int r = u / (28*32); int rem = u - r*(28*32);
        int j = rem >> 5, c = rem & 31;
        *(short8*)&Qs[(r*28 + j)*256 + c*8] =
            *(const short8*)(qbuf + ((size_t)b*784 + (i0+r)*28 + j)*256 + c*8);
    }
    __syncthreads();

    float scale = expf(g_tau[0]);
    if (tid < 252){
        int pix = tid / 9, l = tid - (tid/9)*9;
        int j0 = min(max(pix-1,0),25);
        int qr = l/3, qj = j0 + (l - qr*3);
        const short* kp = &Ks[pix*256];
        const short* qp = &Qs[(qr*28 + qj)*256];
        float p = 0.f;
        for (int c = 0; c < 32; c++){
            short8 k8 = *(const short8*)(kp + c*8);
            short8 q8 = *(const short8*)(qp + c*8);
            #pragma unroll
            for (int d=0; d<8; d++) p += s2f(k8[d])*s2f(q8[d]);
        }
        sc[pix*9 + l] = sanit((p + rpb[n*9+l])*scale);
    }
    __syncthreads();
    if (tid < 28){
        float m = -1e30f;
        for (int l=0;l<9;l++) m = fmaxf(m, sc[tid*9+l]);
        float sum=0.f; float e[9];
        for (int l=0;l<9;l++){ e[l]=expf(sc[tid*9+l]-m); sum+=e[l]; }
        float inv = 1.f/fmaxf(sum,1e-30f);
        for (int l=0;l<9;l++) pr[tid*9+l] = e[l]*inv + 1e-6f;
    }
    __syncthreads();
    if (tid < 252){
        int pix = tid/9, l = tid - (tid/9)*9;
        float a = pr[pix*9+l];
        int idx = (b*4+n)*784 + i*28 + pix;
        attn[(size_t)idx*9 + l] = a;
        int j0 = min(max(pix-1,0),25);
        int qi = i0 + l/3, qj = j0 + l%3;
        atomicAdd(&col[b*784 + qi*28 + qj], a);
    }
}

__global__ void grp_av_kernel(const float* __restrict__ attn, const float* __restrict__ col,
                              const bf16* __restrict__ vproj, float* __restrict__ xout,
                              bf16* __restrict__ xouth)
{
    int idx = blockIdx.x;   // b*784 + i*28 + j
    int j = idx%28; int i = (idx/28)%28; int b = idx/784;
    int d = threadIdx.x;
    int i0 = min(max(i-1,0),25), j0 = min(max(j-1,0),25);
    float acc = 0.f;
    for (int n=0; n<4; n++){
        int sh = n>>1, sw = n&1;
        const float* ap = attn + ((size_t)(b*4+n)*784 + i*28+j)*9;
        for (int l=0; l<9; l++){
            int qi = i0 + l/3, qj = j0 + l%3;
            float dv = col[b*784 + qi*28+qj] + 1e-8f;
            acc += (ap[l]/dv) * b2f(vproj[((size_t)b*3136 + (2*qi+sh)*56 + (2*qj+sw))*256 + d]);
        }
    }
    size_t o = (size_t)idx*256 + d;
    float nv = xout[o] + acc;
    xout[o] = nv;
    xouth[o] = __float2bfloat16(nv);
}

// ------- Block attention (KB=7), row-tiled, RoPE fused in staging ---------
__global__ __launch_bounds__(256) void blk_attn_row(const bf16* __restrict__ qkv,
                                                    bf16* __restrict__ obuf)
{
    int blk = blockIdx.x;             // (b*28 + i)*8 + h
    int h = blk & 7; int rest = blk >> 3;
    int i = rest % 28; int b = rest / 28;
    int tid = threadIdx.x;
    int i0 = min(max(i-3,0),21);

    __shared__ float Ks[7*28*32];
    __shared__ float Vs[7*28*32];
    __shared__ float Qs[28*32];
    __shared__ float Ps[28*52];

    const float LOG1E4_16 = 0.5756462732485115f;   // ln(10000)/16

    for (int idx = tid; idx < 196*4; idx += 256){
        int pos = idx >> 2, u8 = idx & 3;
        int ki = i0 + pos/28, kj = pos - (pos/28)*28;
        int ttok = ki*28 + kj;
        const bf16* base = qkv + ((size_t)(b*784 + ttok))*768 + h*32 + u8*8;
        short8 k8 = *(const short8*)(base + 256);
        short8 v8 = *(const short8*)(base + 512);
        float f[8];
        #pragma unroll
        for (int d=0; d<8; d++) f[d] = s2f(k8[d]);
        #pragma unroll
        for (int m2=0; m2<4; m2++){
            int u = u8*4 + m2;
            float ang = (float)ttok * expf(-(float)u * LOG1E4_16);
            float c = cosf(ang), s = sinf(ang);
            float x0 = f[2*m2], x1 = f[2*m2+1];
            f[2*m2]   = x0*c - x1*s;
            f[2*m2+1] = x1*c + x0*s;
        }
        #pragma unroll
        for (int d=0; d<8; d++){
            Ks[pos*32 + u8*8 + d] = f[d];
            Vs[pos*32 + u8*8 + d] = s2f(v8[d]);
        }
    }
    for (int idx = tid; idx < 28*4; idx += 256){
        int tt = idx >> 2, u8 = idx & 3;
        int ttok = i*28 + tt;
        const bf16* base = qkv + ((size_t)(b*784 + ttok))*768 + h*32 + u8*8;
        short8 q8 = *(const short8*)base;
        float f[8];
        #pragma unroll
        for (int d=0; d<8; d++) f[d] = s2f(q8[d]);
        #pragma unroll
        for (int m2=0; m2<4; m2++){
            int u = u8*4 + m2;
            float ang = (float)ttok * expf(-(float)u * LOG1E4_16);
            float c = cosf(ang), s = sinf(ang);
            float x0 = f[2*m2], x1 = f[2*m2+1];
            f[2*m2]   = x0*c - x1*s;
            f[2*m2+1] = x1*c + x0*s;
        }
        #pragma unroll
        for (int d=0; d<8; d++) Qs[tt*32 + u8*8 + d] = f[d];
    }
    __syncthreads();

    int tt = tid >> 3, s = tid & 7;
    float sc[7];
    float mx = -1e30f;
    int j0 = min(max(tt-3,0),21);
    if (tt < 28){
        int c = 0;
        for (int l = s; l < 49; l += 8, c++){
            int ki = l/7, kj = j0 + l - (l/7)*7;
            const float4* kp = (const float4*)&Ks[(ki*28+kj)*32];
            const float4* qp = (const float4*)&Qs[tt*32];
            float p = 0.f;
            #pragma unroll
            for (int d=0; d<8; d++){
                float4 kv4 = kp[d], qv4 = qp[d];
                p += qv4.x*kv4.x + qv4.y*kv4.y + qv4.z*kv4.z + qv4.w*kv4.w;
            }
            sc[c] = sanit(p * 0.17677669529663687f);
            mx = fmaxf(mx, sc[c]);
        }
    }
    #pragma unroll
    for (int off=1; off<8; off<<=1) mx = fmaxf(mx, __shfl_xor(mx, off, 8));
    float sm = 0.f;
    if (tt < 28){
        int c = 0;
        for (int l = s; l < 49; l += 8, c++){ sc[c] = expf(sc[c]-mx); sm += sc[c]; }
    }
    #pragma unroll
    for (int off=1; off<8; off<<=1) sm += __shfl_xor(sm, off, 8);
    if (tt < 28){
        float inv = 1.f/fmaxf(sm, 1e-30f);
        int c = 0;
        for (int l = s; l < 49; l += 8, c++) Ps[tt*52 + l] = sc[c]*inv;
    }
    __syncthreads();

    for (int o = tid; o < 28*32; o += 256){
        int t2 = o >> 5, d = o & 31;
        int jj0 = min(max(t2-3,0),21);
        float acc = 0.f;
        #pragma unroll 7
        for (int l=0; l<49; l++){
            int ki = l/7, kj = jj0 + l - (l/7)*7;
            acc += Ps[t2*52 + l] * Vs[(ki*28+kj)*32 + d];
        }
        obuf[((size_t)(b*784 + i*28 + t2))*256 + h*32 + d] = __float2bfloat16(acc);
    }
}

// ==========================================================================
extern "C" void kernel_launch(void* const* d_in, const int* in_sizes, int n_in,
                              void* d_out, int out_size, void* d_ws, size_t ws_size,
                              hipStream_t stream) {
    const float* x         = (const float*)d_in[0];
    const float* g_seed_w  = (const float*)d_in[1];
    const float* g_q_w     = (const float*)d_in[2];
    const float* g_k_w     = (const float*)d_in[3];
    const float* g_v_w     = (const float*)d_in[4];
    const float* g_mlp_w1  = (const float*)d_in[5];
    const float* g_mlp_b1  = (const float*)d_in[6];
    const float* g_mlp_w2  = (const float*)d_in[7];
    const float* g_mlp_b2  = (const float*)d_in[8];
    const float* g_ln_in_g = (const float*)d_in[9];
    const float* g_ln_in_b = (const float*)d_in[10];
    const float* g_ln_out_g= (const float*)d_in[11];
    const float* g_ln_out_b= (const float*)d_in[12];
    const float* g_tau     = (const float*)d_in[13];
    const float* g_rpb     = (const float*)d_in[14];
    const float* blk_ln1_g = (const float*)d_in[15];
    const float* blk_ln1_b = (const float*)d_in[16];
    const float* blk_qkv_w = (const float*)d_in[17];
    const float* blk_proj_w= (const float*)d_in[18];
    const float* blk_proj_b= (const float*)d_in[19];
    const float* blk_ln2_g = (const float*)d_in[20];
    const float* blk_ln2_b = (const float*)d_in[21];
    const float* blk_mlp_w1= (const float*)d_in[22];
    const float* blk_mlp_b1= (const float*)d_in[23];
    const float* blk_mlp_w2= (const float*)d_in[24];
    const float* blk_mlp_b2= (const float*)d_in[25];

    // workspace layout — 11,732,288 floats = 46.9 MB (ws ≈ 268 MB)
    float* f      = (float*)d_ws;
    bf16*  wbuf   = (bf16*)d_ws;                 // 2359296 bf16 = 1179648 f
    bf16*  kproj  = (bf16*)(f + 1179648);        // 3211264 bf16
    bf16*  vproj  = (bf16*)(f + 2785280);        // 3211264 bf16
    float* xout   = f + 4390912;                 // 802816
    float* tmp    = f + 5193728;                 // 802816
    bf16*  tmph   = (bf16*)(f + 5996544);        // 802816 bf16
    bf16*  qbufh  = (bf16*)(f + 6397952);        // 802816 bf16
    bf16*  bigh   = (bf16*)(f + 6799360);        // 2408448 bf16
    float* attng  = f + 8003584;                 // 112896
    float* col    = f + 8116480;                 // 3136
    bf16*  xln    = (bf16*)(f + 8119616);        // 3211264 bf16
    bf16*  xh     = (bf16*)(f + 9725248);        // 3211264 bf16
    bf16*  xouth  = (bf16*)(f + 11330880);       // 802816 bf16

    bf16* w_q    = wbuf;
    bf16* w_k    = wbuf + 65536;
    bf16* w_v    = wbuf + 131072;
    bf16* w_m1   = wbuf + 196608;
    bf16* w_m2   = wbuf + 327680;
    bf16* w_qkv  = wbuf + 458752;   // 2 layers x 196608
    bf16* w_proj = wbuf + 851968;   // 2 x 65536
    bf16* w_bm1  = wbuf + 983040;   // 2 x 196608
    bf16* w_bm2  = wbuf + 1376256;  // 2 x 196608
    bf16* w_seed = wbuf + 1769472;  // 589824

    // ---- setup: 1 fused dispatch, then merged kv+conv dispatch ----
    setup_fused<<<21760, 256, 0, stream>>>(x, g_ln_in_g, g_ln_in_b, xln, xh, tmp,
                                           g_q_w, g_k_w, g_v_w, g_mlp_w1, g_mlp_w2,
                                           blk_qkv_w, blk_proj_w, blk_mlp_w1, blk_mlp_w2,
                                           wbuf, g_seed_w, w_seed);
    kv_conv<<<dim3(4,392,3), 128, 0, stream>>>(xln, xh, w_k, w_v, kproj, vproj, w_seed, tmp);
    // xout = LN_out(seed); tmph = LN_out(xout); col = 0
    ln_add_ln<<<3136, 256, 0, stream>>>(tmp, nullptr, g_ln_out_g, g_ln_out_b,
                                        g_ln_out_g, g_ln_out_b, xout, tmph, col);

    // ---- NUM_ITERS group-attention iterations ----
    for (int it=0; it<3; it++){
        gemm_mfma<bf16,bf16><<<dim3(4,98), 128, 0, stream>>>(tmph, w_q, nullptr, nullptr, qbufh, 3136,256,256, 0);
        grp_attn_row<<<448, 256, 0, stream>>>(kproj, qbufh, g_rpb, g_tau, attng, col);
        grp_av_kernel<<<3136, 256, 0, stream>>>(attng, col, vproj, xout, xouth);
        gemm_mfma<bf16,bf16><<<dim3(8,98), 128, 0, stream>>>(xouth, w_m1, g_mlp_b1, nullptr, bigh, 3136,512,256, 1);
        gemm_mfma<bf16,float><<<dim3(4,98), 128, 0, stream>>>(bigh, w_m2, g_mlp_b2, nullptr, tmp, 3136,256,512, 0);
        const float* g2 = (it<2) ? g_ln_out_g : blk_ln1_g;   // it=2 feeds blk layer 0 LN1
        const float* b2 = (it<2) ? g_ln_out_b : blk_ln1_b;
        ln_add_ln<<<3136, 256, 0, stream>>>(tmp, xout, g_ln_out_g, g_ln_out_b,
                                            g2, b2, xout, tmph, col);
    }

    // ---- DEPTH transformer blocks (tmph holds LN1(xout) at loop entry) ----
    for (int l=0; l<2; l++){
        gemm_mfma<bf16,bf16><<<dim3(12,98), 128, 0, stream>>>(tmph, w_qkv + (size_t)l*196608, nullptr, nullptr, bigh, 3136,768,256, 0);
        blk_attn_row<<<896, 256, 0, stream>>>(bigh, qbufh);
        gemm_mfma<bf16,float><<<dim3(4,98), 128, 0, stream>>>(qbufh, w_proj + (size_t)l*65536, blk_proj_b + l*256, xout, xout, 3136,256,256, 0);
        ln256_kernel<bf16><<<3136, 256, 0, stream>>>(xout, blk_ln2_g + l*256, blk_ln2_b + l*256, tmph, 0);
        gemm_mfma<bf16,bf16><<<dim3(12,98), 128, 0, stream>>>(tmph, w_bm1 + (size_t)l*196608, blk_mlp_b1 + l*768, nullptr, bigh, 3136,768,256, 1);
        if (l==0){
            gemm_mfma<bf16,float><<<dim3(4,98), 128, 0, stream>>>(bigh, w_bm2, blk_mlp_b2, xout, xout, 3136,256,768, 0);
            ln256_kernel<bf16><<<3136, 256, 0, stream>>>(xout, blk_ln1_g + 256, blk_ln1_b + 256, tmph, 0);
        } else {
            gemm_mfma<bf16,float><<<dim3(4,98), 128, 0, stream>>>(bigh, w_bm2 + 196608, blk_mlp_b2 + 256, xout, (float*)d_out, 3136,256,768, 0);
        }
    }
}